// Round 15
// baseline (362.947 us; speedup 1.0000x reference)
//
#include <hip/hip_runtime.h>
#include <hip/hip_bf16.h>
#include <math.h>

typedef __attribute__((ext_vector_type(8))) short short8;
typedef __attribute__((ext_vector_type(4))) float f32x4;
typedef __attribute__((ext_vector_type(4))) unsigned short us4;
typedef unsigned short u16;
typedef unsigned long long u64;

#define TM 49
#define NV 10000
#define NLSTM 64
#define NFC 192
#define SMEM_BYTES 133184

union U64c { us4 v; u64 u; };

__device__ __forceinline__ u16 f2bf(float f) {
    union { float f; unsigned u; } v; v.f = f;
    unsigned r = v.u + 0x7fffu + ((v.u >> 16) & 1u);
    return (u16)(r >> 16);
}
__device__ __forceinline__ float fsigm(float x) {
    return 1.0f / (1.0f + __expf(-x));
}
__device__ __forceinline__ float ftanh(float x) {
    float x2 = fminf(fmaxf(x + x, -30.0f), 30.0f);
    float e = __expf(x2);
    return (e - 1.0f) / (e + 1.0f);
}

// coherence-point access helpers (sc0 sc1 = bypass L1+L2, device coherence point)
__device__ __forceinline__ short8 ld_cp128(const u16* p) {
    short8 r;
    asm volatile("global_load_dwordx4 %0, %1, off sc0 sc1" : "=v"(r) : "v"(p));
    return r;   // caller must s_waitcnt before use
}
__device__ __forceinline__ void st_cp64(u16* p, us4 v) {
    U64c u; u.v = v;
    asm volatile("global_store_dwordx2 %0, %1, off sc0 sc1" :: "v"(p), "v"(u.u) : "memory");
}
__device__ __forceinline__ void st_cp32f(float* p, float v) {
    asm volatile("global_store_dword %0, %1, off sc0 sc1" :: "v"(p), "v"(v) : "memory");
}
__device__ __forceinline__ void st_cp32u(unsigned* p, unsigned v) {
    asm volatile("global_store_dword %0, %1, off sc0 sc1" :: "v"(p), "v"(v) : "memory");
}
__device__ __forceinline__ unsigned ld_cp32_wait(const unsigned* p) {
    unsigned r;
    asm volatile("global_load_dword %0, %1, off sc0 sc1\n\ts_waitcnt vmcnt(0)"
                 : "=v"(r) : "v"(p) : "memory");
    return r;
}

// ---------------- sort + metadata + compaction tables + small outputs ----------------
__global__ __launch_bounds__(128) void k_sort(
    const int* __restrict__ caplens, const int* __restrict__ captions,
    const float* __restrict__ bih, const float* __restrict__ bhh,
    int* __restrict__ sidx, int* __restrict__ decl, int* __restrict__ capsS,
    float* __restrict__ bsum, float* __restrict__ out_tail,
    unsigned* __restrict__ flags, unsigned* __restrict__ xcnt,
    int* __restrict__ offs, int* __restrict__ rowmap, int* __restrict__ maskmap)
{
    __shared__ int s_cl[128];
    __shared__ int s_si[128];
    __shared__ int s_dl[128];
    __shared__ int s_n[49];
    __shared__ int s_off[50];
    __shared__ int s_moff[128];
    int tid = threadIdx.x;
    if (tid < 64)   // reset 64 packed per-WG flags (group rb = one 64B line)
        __hip_atomic_store(&flags[tid], 0u, __ATOMIC_RELAXED, __HIP_MEMORY_SCOPE_AGENT);
    for (int k = tid; k < 1568; k += 128)   // reset per-t X counters
        __hip_atomic_store(&xcnt[k], 0u, __ATOMIC_RELAXED, __HIP_MEMORY_SCOPE_AGENT);
    int my = caplens[tid];
    s_cl[tid] = my;
    __syncthreads();
    int r = 0;
    for (int j = 0; j < 128; j++) {
        int cj = s_cl[j];
        if (cj > my || (cj == my && j < tid)) r++;
    }
    s_si[r] = tid;   // stable descending argsort
    __syncthreads();
    int src = s_si[tid];
    sidx[tid] = src;
    int dl = s_cl[src] - 1;
    decl[tid] = dl;
    s_dl[tid] = dl;
    out_tail[6400 + tid] = (float)dl;
    out_tail[6528 + tid] = (float)src;
    for (int t = 0; t < 50; t++) {
        int tok = captions[src * 50 + t];
        capsS[tid * 50 + t] = tok;
        out_tail[tid * 50 + t] = (float)tok;
    }
    for (int k = tid; k < 2048; k += 128) bsum[k] = bih[k] + bhh[k];
    __syncthreads();
    if (tid < 49) {
        int c = 0;
        for (int b = 0; b < 128; b++) c += (s_dl[b] > tid);
        s_n[tid] = c;
    }
    __syncthreads();
    if (tid == 0) {
        int a = 0;
        for (int t = 0; t < 49; t++) { s_off[t] = a; a += s_n[t]; }
        s_off[49] = a;   // total compacted rows
        int m = 0;
        for (int b = 0; b < 128; b++) { s_moff[b] = m; m += 49 - s_dl[b]; }
    }
    __syncthreads();
    if (tid < 50) offs[tid] = s_off[tid];
    for (int t = 0; t < dl; t++) rowmap[s_off[t] + tid] = t * 128 + tid;
    int mo = s_moff[tid];
    for (int t = dl; t < 49; t++) maskmap[mo + (t - dl)] = tid * 49 + t;
}

// ---------------- weight fp32 -> bf16 conversion ----------------
__global__ __launch_bounds__(256) void k_cvt(
    const float* __restrict__ Wih, const float* __restrict__ Whh,
    const float* __restrict__ fcW, const float* __restrict__ ihW,
    const float* __restrict__ icW,
    u16* __restrict__ WihB, u16* __restrict__ WhhB,
    u16* __restrict__ fcWB, u16* __restrict__ WhcB)
{
    int idx = blockIdx.x * 256 + threadIdx.x;  // float4 index, exact grid
    const float* src; u16* dst; int o;
    if (idx < 262144)        { src = Wih; dst = WihB; o = idx; }
    else if (idx < 524288)   { src = Whh; dst = WhhB; o = idx - 262144; }
    else if (idx < 1804288)  { src = fcW; dst = fcWB; o = idx - 524288; }
    else if (idx < 2066432)  { src = ihW; dst = WhcB; o = idx - 1804288; }
    else                     { src = icW; dst = WhcB + 1048576; o = idx - 2066432; }
    f32x4 v = *(const f32x4*)&src[(size_t)o * 4];
    us4 b = { f2bf(v.x), f2bf(v.y), f2bf(v.z), f2bf(v.w) };
    *(us4*)&dst[(size_t)o * 4] = b;
}

// ---------------- gathers: sorted enc -> bf16, embedding -> bf16 ----------------
__global__ __launch_bounds__(256) void k_gather(
    const float* __restrict__ enc, const float* __restrict__ embW,
    const int* __restrict__ sidx, const int* __restrict__ capsS,
    u16* __restrict__ encB, u16* __restrict__ Xemb)
{
    int idx = blockIdx.x * 256 + threadIdx.x;
    if (idx < 65536) {
        int b = idx >> 9, k4 = idx & 511;
        f32x4 v = *(const f32x4*)&enc[(size_t)sidx[b] * 2048 + k4 * 4];
        us4 o = { f2bf(v.x), f2bf(v.y), f2bf(v.z), f2bf(v.w) };
        *(us4*)&encB[(size_t)b * 2048 + k4 * 4] = o;
    } else {
        int j = idx - 65536;              // < 802816
        int row = j >> 7, k4 = j & 127;   // row = t*128 + b
        int t = row >> 7, b = row & 127;
        int tok = capsS[b * 50 + t];
        f32x4 v = *(const f32x4*)&embW[(size_t)tok * 512 + k4 * 4];
        us4 o = { f2bf(v.x), f2bf(v.y), f2bf(v.z), f2bf(v.w) };
        *(us4*)&Xemb[(size_t)row * 512 + k4 * 4] = o;
    }
}

// ---- shared 128x128 tile GEMM body (plain loads, full 128 valid rows both sides) ----
__device__ __forceinline__ void tile_gemm_plain(
    const u16* __restrict__ A, int lda, const u16* __restrict__ B, int ldb,
    int K, int tid, u16 (*As)[40], u16 (*Bs)[40], f32x4 acc[4][4])
{
    const int w = tid >> 6, l = tid & 63;
    const int wr = (w >> 1) * 64, wc = (w & 1) * 64;
    const int lr = l & 15, lg = l >> 4;
    for (int k0 = 0; k0 < K; k0 += 32) {
        __syncthreads();
        #pragma unroll
        for (int i = 0; i < 2; i++) {
            int L = tid * 8 + i * 2048;
            int r = L >> 5, c = L & 31;
            *(short8*)&As[r][c] = *(const short8*)&A[(size_t)r * lda + k0 + c];
            *(short8*)&Bs[r][c] = *(const short8*)&B[(size_t)r * ldb + k0 + c];
        }
        __syncthreads();
        short8 af[4], bfr[4];
        #pragma unroll
        for (int m = 0; m < 4; m++) af[m] = *(const short8*)&As[wr + m * 16 + lr][lg * 8];
        #pragma unroll
        for (int n = 0; n < 4; n++) bfr[n] = *(const short8*)&Bs[wc + n * 16 + lr][lg * 8];
        #pragma unroll
        for (int m = 0; m < 4; m++)
            #pragma unroll
            for (int n = 0; n < 4; n++)
                acc[m][n] = __builtin_amdgcn_mfma_f32_16x16x32_bf16(af[m], bfr[n], acc[m][n], 0, 0, 0);
    }
}

// ---------------- fused persistent kernel ----------------
// blocks 0..63:   LSTM producers with TRANSPOSED MFMA (acc = mfma(W_frag, h_frag)):
//                 each thread owns ONE batch row x 4 consecutive hidden cols ->
//                 vector X loads (4x f32x4), single 8B h-store, single 8B HnewC
//                 store, thread-uniform act. Flags packed: group rb = one 64B line.
// blocks 64..255: consumers. Phase 1: 784 X tiles (post xcnt[t]). Phase 2: fc
//                 column-owner; gate = 64-lane coalesced flag read >= tmax+3;
//                 gate-waits consumed by zero-fill (non-temporal stores).
__global__ __launch_bounds__(256, 1) void lstm_fc(
    const u16* __restrict__ Whh, float* __restrict__ X,
    u16* __restrict__ hb0, u16* __restrict__ hb1,
    u16* __restrict__ HnewC,
    const int* __restrict__ decl, unsigned* __restrict__ flags,
    unsigned* __restrict__ xcnt,
    const int* __restrict__ offs, const int* __restrict__ rowmap,
    const int* __restrict__ maskmap,
    const u16* __restrict__ fcWB, const float* __restrict__ fcb,
    const u16* __restrict__ encB, const u16* __restrict__ WhcB,
    const u16* __restrict__ WihB, const u16* __restrict__ Xemb,
    const float* __restrict__ bsum,
    const float* __restrict__ ihb, const float* __restrict__ icb,
    float* __restrict__ out)
{
    extern __shared__ char smem[];
    const int tid = threadIdx.x;
    const int wg = blockIdx.x;

    if (wg < NLSTM) {
        // ======================= recurrence producer =======================
        u16 (*As)[520] = (u16(*)[520])smem;              // 33280 B
        u16 (*Bsi)[520] = (u16(*)[520])(smem + 33280);   // 33280 B (init only)
        const int rb = wg >> 4, cb = wg & 15;
        const int w = tid >> 6, l = tid & 63;
        const int hi = w >> 1, lo = w & 1;
        const int lr = l & 15, lg = l >> 4;
        unsigned* myflag = &flags[wg];

        const int r = rb * 32 + hi * 16 + lr;          // thread-owned batch row
        const int col0 = cb * 32 + lo * 16 + lg * 4;   // first of 4 owned cols

        // ---- init: h0/c0 (K=2048, 4 chunks), TRANSPOSED mfma(W, enc) ----
        f32x4 acch = {}, accc = {};
        for (int kq = 0; kq < 4; kq++) {
            __syncthreads();
            #pragma unroll
            for (int i = 0; i < 8; i++) {
                int L = tid * 8 + i * 2048;
                int rr = L >> 9, cc = L & 511;
                *(short8*)&As[rr][cc] =
                    *(const short8*)&encB[(size_t)(rb * 32 + rr) * 2048 + kq * 512 + cc];
                *(short8*)&Bsi[rr][cc] =
                    *(const short8*)&WhcB[(size_t)(cb * 32 + rr) * 2048 + kq * 512 + cc];
            }
            __syncthreads();
            #pragma unroll
            for (int kk = 0; kk < 16; kk++) {
                short8 a = *(const short8*)&As[hi * 16 + lr][kk * 32 + lg * 8];
                short8 b = *(const short8*)&Bsi[lo * 16 + lr][kk * 32 + lg * 8];
                acch = __builtin_amdgcn_mfma_f32_16x16x32_bf16(b, a, acch, 0, 0, 0);
            }
            __syncthreads();
            #pragma unroll
            for (int i = 0; i < 8; i++) {
                int L = tid * 8 + i * 2048;
                int rr = L >> 9, cc = L & 511;
                *(short8*)&Bsi[rr][cc] =
                    *(const short8*)&WhcB[(size_t)(512 + cb * 32 + rr) * 2048 + kq * 512 + cc];
            }
            __syncthreads();
            #pragma unroll
            for (int kk = 0; kk < 16; kk++) {
                short8 a = *(const short8*)&As[hi * 16 + lr][kk * 32 + lg * 8];
                short8 b = *(const short8*)&Bsi[lo * 16 + lr][kk * 32 + lg * 8];
                accc = __builtin_amdgcn_mfma_f32_16x16x32_bf16(b, a, accc, 0, 0, 0);
            }
        }

        const int edec = decl[r];
        f32x4 creg;
        us4 hreg;
        {
            f32x4 ihb4 = *(const f32x4*)&ihb[col0];
            f32x4 icb4 = *(const f32x4*)&icb[col0];
            #pragma unroll
            for (int i = 0; i < 4; i++) {
                creg[i] = accc[i] + icb4[i];
                hreg[i] = f2bf(acch[i] + ihb4[i]);
            }
            st_cp64(&hb0[(size_t)r * 512 + col0], hreg);
        }
        asm volatile("s_waitcnt vmcnt(0)" ::: "memory");
        __syncthreads();
        if (tid == 0) st_cp32u(myflag, 1u);   // init published

        // ---- Whh fragments into registers (plain; L2/L3) ----
        short8 bq[4][16];
        #pragma unroll
        for (int q = 0; q < 4; q++) {
            const u16* base = &Whh[(size_t)(q * 512 + cb * 32 + lo * 16 + lr) * 512 + lg * 8];
            #pragma unroll
            for (int kk = 0; kk < 16; kk++)
                bq[q][kk] = *(const short8*)&base[kk * 32];
        }
        #pragma unroll
        for (int q = 0; q < 4; q++)
            #pragma unroll
            for (int kk = 0; kk < 16; kk++)
                asm volatile("" : "+v"(bq[q][kk]));   // pin: no remat of weight loads

        for (int t = 0; t < TM; t++) {
            const u16* hin = (t & 1) ? hb1 : hb0;
            u16* hout = (t & 1) ? hb0 : hb1;

            // gate: 16 flag lanes (one coalesced 64B line) + lane 16 (X[t])
            if (tid < 64) {
                unsigned tgt_h = (unsigned)(t + 1);
                while (true) {
                    bool ok = true;
                    if (tid < 16)
                        ok = (ld_cp32_wait(&flags[rb * 16 + tid]) >= tgt_h);
                    else if (tid == 16)
                        ok = (ld_cp32_wait(&xcnt[t * 32]) >= 16u);
                    if (__all(ok)) break;
                }
            }
            __syncthreads();

            // X[t] gate addends: 4 vector loads (plain; first touch fresh)
            f32x4 xq[4];
            #pragma unroll
            for (int q = 0; q < 4; q++)
                xq[q] = *(const f32x4*)&X[(size_t)t * 262144 + (size_t)r * 2048 + q * 512 + col0];
            int offt = offs[t];

            // stage 32x512 h tile: 8 pipelined sc0sc1 x4 loads, one drain, LDS writes
            short8 tmp[8];
            #pragma unroll
            for (int i = 0; i < 8; i++) {
                int L = i * 256 + tid;          // 16B-chunk index; 2048 total
                int rr = L >> 6, cc = (L & 63) * 8;
                tmp[i] = ld_cp128(&hin[(size_t)(rb * 32 + rr) * 512 + cc]);
            }
            asm volatile("s_waitcnt vmcnt(0)" ::: "memory");
            __builtin_amdgcn_sched_barrier(0);
            #pragma unroll
            for (int i = 0; i < 8; i++) {
                int L = i * 256 + tid;
                int rr = L >> 6, cc = (L & 63) * 8;
                *(short8*)&As[rr][cc] = tmp[i];
            }
            __syncthreads();

            // TRANSPOSED: acc[q] = W_slice^T x h^T -> thread = (row r, 4 cols)
            f32x4 acc[4] = {};
            #pragma unroll
            for (int kk = 0; kk < 16; kk++) {
                short8 a = *(const short8*)&As[hi * 16 + lr][kk * 32 + lg * 8];
                acc[0] = __builtin_amdgcn_mfma_f32_16x16x32_bf16(bq[0][kk], a, acc[0], 0, 0, 0);
                acc[1] = __builtin_amdgcn_mfma_f32_16x16x32_bf16(bq[1][kk], a, acc[1], 0, 0, 0);
                acc[2] = __builtin_amdgcn_mfma_f32_16x16x32_bf16(bq[2][kk], a, acc[2], 0, 0, 0);
                acc[3] = __builtin_amdgcn_mfma_f32_16x16x32_bf16(bq[3][kk], a, acc[3], 0, 0, 0);
            }

            // row-local epilogue; one 8B h-store per thread (sc0sc1, before drain)
            const int act = (t < edec);
            #pragma unroll
            for (int i = 0; i < 4; i++) {
                float iv = fsigm(acc[0][i] + xq[0][i]);
                float fv = fsigm(acc[1][i] + xq[1][i]);
                float gv = ftanh(acc[2][i] + xq[2][i]);
                float ov = fsigm(acc[3][i] + xq[3][i]);
                float cn = fv * creg[i] + iv * gv;
                float hn_f = ov * ftanh(cn);
                if (act) {
                    creg[i] = cn;
                    hreg[i] = f2bf(hn_f);
                }
            }
            st_cp64(&hout[(size_t)r * 512 + col0], hreg);

            // drain h stores, post flag, THEN deferred HnewC store (covered by
            // next step's drain / final drain)
            asm volatile("s_waitcnt vmcnt(0)" ::: "memory");
            __syncthreads();
            if (tid == 0) st_cp32u(myflag, (unsigned)(t + 2));
            if (act)
                st_cp64(&HnewC[(size_t)(offt + r) * 512 + col0], hreg);
        }

        // final: drain deferred HnewC stores, publish terminal flag
        asm volatile("s_waitcnt vmcnt(0)" ::: "memory");
        __syncthreads();
        if (tid == 0) st_cp32u(myflag, (unsigned)(TM + 2));
    } else {
        // ======================= consumer =======================
        const int f = wg - NLSTM;
        const int w = tid >> 6, l = tid & 63;
        const int wr = (w >> 1) * 64, wc = (w & 1) * 64;
        const int lr = l & 15, lg = l >> 4;

        int nrC = offs[49];
        int nzero = 6272 - nrC;
        int nrt = (nrC + 127) >> 7;

        // ---- phase 1: X tiles (784 jobs round-robin) ----
        {
            u16 (*As)[40] = (u16(*)[40])smem;
            u16 (*Bs)[40] = (u16(*)[40])(smem + 10240);
            for (int j = f; j < 784; j += NFC) {
                int tt = j >> 4, cbx = j & 15;
                f32x4 acc[4][4] = {};
                tile_gemm_plain(Xemb + (size_t)tt * 128 * 512, 512,
                                WihB + (size_t)cbx * 128 * 512, 512,
                                512, tid, As, Bs, acc);
                #pragma unroll
                for (int m = 0; m < 4; m++)
                    #pragma unroll
                    for (int n = 0; n < 4; n++)
                        #pragma unroll
                        for (int i = 0; i < 4; i++) {
                            int row = wr + m * 16 + lg * 4 + i;
                            int colg = cbx * 128 + wc + n * 16 + lr;
                            st_cp32f(&X[(size_t)tt * 262144 + (size_t)row * 2048 + colg],
                                     acc[m][n][i] + bsum[colg]);
                        }
                asm volatile("s_waitcnt vmcnt(0)" ::: "memory");
                __syncthreads();
                if (tid == 0) atomicAdd(&xcnt[tt * 32], 1u);
            }
        }

        // ---- phase 2: fc column-owner; B panel resident in LDS; gate-waits
        //      consumed by opportunistic zero-fill of masked out rows ----
        int c = f % 79;               // owned column tile
        int sub = f / 79;             // 0,1 (2 only for c < 34)
        int gsize = (c < 34) ? 3 : 2;

        u16 (*BT)[520] = (u16(*)[520])smem;                 // 133120 B
        unsigned* s_rdy = (unsigned*)(smem + 133120);       // 1 u32
        __syncthreads();   // phase-1 LDS fully retired before overwrite
        #pragma unroll
        for (int i = 0; i < 32; i++) {
            int L = i * 256 + tid;            // short8 index; 8192 = 128 x 64
            int rr = L >> 6, cc = (L & 63) * 8;
            int gn = c * 128 + rr;
            short8 b = {};
            if (gn < NV) b = *(const short8*)&fcWB[(size_t)gn * 512 + cc];
            *(short8*)&BT[rr][cc] = b;
        }
        __syncthreads();

        int znext = f;   // this consumer's masked-row zero jobs: f, f+NFC, ...
        f32x4 zv = {};

        for (int rt = sub; rt < nrt; rt += gsize) {
            int lastrow = min(rt * 128 + 127, nrC - 1);
            int tmax = rowmap[lastrow] >> 7;
            unsigned tgt = (unsigned)(tmax + 3);   // deferred-HnewC visibility

            // gate with productive waiting: 64-lane coalesced flag read
            while (true) {
                bool ok = (tid < 64) ? (ld_cp32_wait(&flags[tid]) >= tgt) : true;
                int allv = __all(ok);
                if (tid == 0) *s_rdy = (unsigned)allv;
                __syncthreads();
                bool rdy = (*s_rdy != 0);
                __syncthreads();
                if (rdy) break;
                if (znext < nzero) {
                    float* dst = out + (size_t)maskmap[znext] * 10000;
                    for (int i = tid; i < 2500; i += 256)
                        __builtin_nontemporal_store(zv, (f32x4*)&dst[i * 4]);
                    znext += NFC;
                } else {
                    __builtin_amdgcn_s_sleep(32);
                }
            }

            // barrier-free K-loop: A fragments direct global->reg, B from LDS
            f32x4 acc[4][4] = {};
            #pragma unroll
            for (int ks = 0; ks < 16; ks++) {
                short8 af[4], bfr[4];
                #pragma unroll
                for (int m = 0; m < 4; m++) {
                    int gr = rt * 128 + wr + m * 16 + lr;
                    short8 a = {};
                    if (gr < nrC)
                        a = *(const short8*)&HnewC[(size_t)gr * 512 + ks * 32 + lg * 8];
                    af[m] = a;
                }
                #pragma unroll
                for (int n = 0; n < 4; n++)
                    bfr[n] = *(const short8*)&BT[wc + n * 16 + lr][ks * 32 + lg * 8];
                #pragma unroll
                for (int m = 0; m < 4; m++)
                    #pragma unroll
                    for (int n = 0; n < 4; n++)
                        acc[m][n] = __builtin_amdgcn_mfma_f32_16x16x32_bf16(af[m], bfr[n], acc[m][n], 0, 0, 0);
            }

            #pragma unroll
            for (int m = 0; m < 4; m++)
                #pragma unroll
                for (int n = 0; n < 4; n++)
                    #pragma unroll
                    for (int i = 0; i < 4; i++) {
                        int row = rt * 128 + wr + m * 16 + lg * 4 + i;
                        int colg = c * 128 + wc + n * 16 + lr;
                        if (row < nrC && colg < NV) {
                            int map = rowmap[row];
                            int b = map & 127, tt = map >> 7;
                            __builtin_nontemporal_store(
                                acc[m][n][i] + fcb[colg],
                                &out[(size_t)(b * 49 + tt) * 10000 + colg]);
                        }
                    }
        }

        // leftover zero jobs
        while (znext < nzero) {
            float* dst = out + (size_t)maskmap[znext] * 10000;
            for (int i = tid; i < 2500; i += 256)
                __builtin_nontemporal_store(zv, (f32x4*)&dst[i * 4]);
            znext += NFC;
        }
    }
}

extern "C" void kernel_launch(void* const* d_in, const int* in_sizes, int n_in,
                              void* d_out, int out_size, void* d_ws, size_t ws_size,
                              hipStream_t stream) {
    const float* enc      = (const float*)d_in[0];
    const int*   captions = (const int*)d_in[1];
    const int*   caplens  = (const int*)d_in[2];
    const float* embW     = (const float*)d_in[3];
    const float* Wih      = (const float*)d_in[4];
    const float* Whh      = (const float*)d_in[5];
    const float* bih      = (const float*)d_in[6];
    const float* bhh      = (const float*)d_in[7];
    const float* fcW      = (const float*)d_in[8];
    const float* fcb      = (const float*)d_in[9];
    const float* ihW      = (const float*)d_in[10];
    const float* ihb      = (const float*)d_in[11];
    const float* icW      = (const float*)d_in[12];
    const float* icb      = (const float*)d_in[13];
    float* out = (float*)d_out;

    char* ws = (char*)d_ws;
    u16*   WihB = (u16*)(ws + 0);
    u16*   WhhB = (u16*)(ws + 2097152);
    u16*   fcWB = (u16*)(ws + 4194304);
    u16*   WhcB = (u16*)(ws + 14434304);
    u16*   encB = (u16*)(ws + 18628608);
    u16*   Xemb = (u16*)(ws + 19152896);
    float* X    = (float*)(ws + 25575424);
    u16*   HnewC= (u16*)(ws + 76955648);
    u16*   hb0  = (u16*)(ws + 83378176);
    u16*   hb1  = (u16*)(ws + 83509248);
    unsigned* flags = (unsigned*)(ws + 83640320);   // 64 packed flags (4 x 64B lines)
    int*   sidx = (int*)(ws + 83902464);
    int*   decl = (int*)(ws + 83902976);
    int*   capsS= (int*)(ws + 83903488);
    float* bsum = (float*)(ws + 83929088);
    int*   offs   = (int*)(ws + 83938304);          // 50 ints; offs[49] = nrowsC
    int*   rowmap = (int*)(ws + 83938560);          // 6272 ints
    int*   maskmap= (int*)(ws + 83963648);          // 6272 ints
    unsigned* xcnt = (unsigned*)(ws + 83988736);    // 49 counters @ t*32

    k_sort<<<1, 128, 0, stream>>>(caplens, captions, bih, bhh, sidx, decl, capsS, bsum,
                                  out + 62720000, flags, xcnt, offs, rowmap, maskmap);
    k_cvt<<<9096, 256, 0, stream>>>(Wih, Whh, fcW, ihW, icW, WihB, WhhB, fcWB, WhcB);
    k_gather<<<3392, 256, 0, stream>>>(enc, embW, sidx, capsS, encB, Xemb);
    // fused: h0/c0 (in producers) + X precompute + zero-fill + 49 steps + fc GEMM
    lstm_fc<<<NLSTM + NFC, 256, SMEM_BYTES, stream>>>(
        WhhB, X, hb0, hb1, HnewC, decl, flags, xcnt, offs, rowmap, maskmap,
        fcWB, fcb, encB, WhcB, WihB, Xemb, bsum, ihb, icb, out);
}

// Round 17
// 331.739 us; speedup vs baseline: 1.0941x; 1.0941x over previous
//
#include <hip/hip_runtime.h>
#include <hip/hip_bf16.h>
#include <math.h>

typedef __attribute__((ext_vector_type(8))) short short8;
typedef __attribute__((ext_vector_type(4))) float f32x4;
typedef __attribute__((ext_vector_type(4))) unsigned short us4;
typedef unsigned short u16;
typedef unsigned long long u64;

#define TM 49
#define NV 10000
#define NLSTM 64
#define NFC 192
#define SMEM_BYTES 133184

__device__ __forceinline__ u16 f2bf(float f) {
    union { float f; unsigned u; } v; v.f = f;
    unsigned r = v.u + 0x7fffu + ((v.u >> 16) & 1u);
    return (u16)(r >> 16);
}
__device__ __forceinline__ float fsigm(float x) {
    return 1.0f / (1.0f + __expf(-x));
}
__device__ __forceinline__ float ftanh(float x) {
    float x2 = fminf(fmaxf(x + x, -30.0f), 30.0f);
    float e = __expf(x2);
    return (e - 1.0f) / (e + 1.0f);
}

// coherence-point access helpers (sc0 sc1 = bypass L1+L2, device coherence point)
__device__ __forceinline__ short8 ld_cp128(const u16* p) {
    short8 r;
    asm volatile("global_load_dwordx4 %0, %1, off sc0 sc1" : "=v"(r) : "v"(p));
    return r;   // caller must s_waitcnt before use
}
__device__ __forceinline__ void st_cp16(u16* p, unsigned v) {
    asm volatile("global_store_short %0, %1, off sc0 sc1" :: "v"(p), "v"(v) : "memory");
}
__device__ __forceinline__ void st_cp32f(float* p, float v) {
    asm volatile("global_store_dword %0, %1, off sc0 sc1" :: "v"(p), "v"(v) : "memory");
}
__device__ __forceinline__ void st_cp32u(unsigned* p, unsigned v) {
    asm volatile("global_store_dword %0, %1, off sc0 sc1" :: "v"(p), "v"(v) : "memory");
}
__device__ __forceinline__ unsigned ld_cp32_wait(const unsigned* p) {
    unsigned r;
    asm volatile("global_load_dword %0, %1, off sc0 sc1\n\ts_waitcnt vmcnt(0)"
                 : "=v"(r) : "v"(p) : "memory");
    return r;
}

// ---------------- sort + metadata + compaction tables + small outputs ----------------
__global__ __launch_bounds__(128) void k_sort(
    const int* __restrict__ caplens, const int* __restrict__ captions,
    const float* __restrict__ bih, const float* __restrict__ bhh,
    int* __restrict__ sidx, int* __restrict__ decl, int* __restrict__ capsS,
    float* __restrict__ bsum, float* __restrict__ out_tail,
    unsigned* __restrict__ flags, unsigned* __restrict__ xcnt,
    int* __restrict__ offs, int* __restrict__ rowmap, int* __restrict__ maskmap)
{
    __shared__ int s_cl[128];
    __shared__ int s_si[128];
    __shared__ int s_dl[128];
    __shared__ int s_n[49];
    __shared__ int s_off[50];
    __shared__ int s_moff[128];
    int tid = threadIdx.x;
    for (int k = tid; k < 2048; k += 128)   // reset 64 per-WG flag lines
        __hip_atomic_store(&flags[k], 0u, __ATOMIC_RELAXED, __HIP_MEMORY_SCOPE_AGENT);
    for (int k = tid; k < 1568; k += 128)   // reset per-t X counters
        __hip_atomic_store(&xcnt[k], 0u, __ATOMIC_RELAXED, __HIP_MEMORY_SCOPE_AGENT);
    int my = caplens[tid];
    s_cl[tid] = my;
    __syncthreads();
    int r = 0;
    for (int j = 0; j < 128; j++) {
        int cj = s_cl[j];
        if (cj > my || (cj == my && j < tid)) r++;
    }
    s_si[r] = tid;   // stable descending argsort
    __syncthreads();
    int src = s_si[tid];
    sidx[tid] = src;
    int dl = s_cl[src] - 1;
    decl[tid] = dl;
    s_dl[tid] = dl;
    out_tail[6400 + tid] = (float)dl;
    out_tail[6528 + tid] = (float)src;
    for (int t = 0; t < 50; t++) {
        int tok = captions[src * 50 + t];
        capsS[tid * 50 + t] = tok;
        out_tail[tid * 50 + t] = (float)tok;
    }
    for (int k = tid; k < 2048; k += 128) bsum[k] = bih[k] + bhh[k];
    __syncthreads();
    if (tid < 49) {
        int c = 0;
        for (int b = 0; b < 128; b++) c += (s_dl[b] > tid);
        s_n[tid] = c;
    }
    __syncthreads();
    if (tid == 0) {
        int a = 0;
        for (int t = 0; t < 49; t++) { s_off[t] = a; a += s_n[t]; }
        s_off[49] = a;   // total compacted rows
        int m = 0;
        for (int b = 0; b < 128; b++) { s_moff[b] = m; m += 49 - s_dl[b]; }
    }
    __syncthreads();
    if (tid < 50) offs[tid] = s_off[tid];
    for (int t = 0; t < dl; t++) rowmap[s_off[t] + tid] = t * 128 + tid;
    int mo = s_moff[tid];
    for (int t = dl; t < 49; t++) maskmap[mo + (t - dl)] = tid * 49 + t;
}

// ---------------- weight fp32 -> bf16 conversion ----------------
__global__ __launch_bounds__(256) void k_cvt(
    const float* __restrict__ Wih, const float* __restrict__ Whh,
    const float* __restrict__ fcW, const float* __restrict__ ihW,
    const float* __restrict__ icW,
    u16* __restrict__ WihB, u16* __restrict__ WhhB,
    u16* __restrict__ fcWB, u16* __restrict__ WhcB)
{
    int idx = blockIdx.x * 256 + threadIdx.x;  // float4 index, exact grid
    const float* src; u16* dst; int o;
    if (idx < 262144)        { src = Wih; dst = WihB; o = idx; }
    else if (idx < 524288)   { src = Whh; dst = WhhB; o = idx - 262144; }
    else if (idx < 1804288)  { src = fcW; dst = fcWB; o = idx - 524288; }
    else if (idx < 2066432)  { src = ihW; dst = WhcB; o = idx - 1804288; }
    else                     { src = icW; dst = WhcB + 1048576; o = idx - 2066432; }
    f32x4 v = *(const f32x4*)&src[(size_t)o * 4];
    us4 b = { f2bf(v.x), f2bf(v.y), f2bf(v.z), f2bf(v.w) };
    *(us4*)&dst[(size_t)o * 4] = b;
}

// ---------------- gathers: sorted enc -> bf16, embedding -> bf16 ----------------
__global__ __launch_bounds__(256) void k_gather(
    const float* __restrict__ enc, const float* __restrict__ embW,
    const int* __restrict__ sidx, const int* __restrict__ capsS,
    u16* __restrict__ encB, u16* __restrict__ Xemb)
{
    int idx = blockIdx.x * 256 + threadIdx.x;
    if (idx < 65536) {
        int b = idx >> 9, k4 = idx & 511;
        f32x4 v = *(const f32x4*)&enc[(size_t)sidx[b] * 2048 + k4 * 4];
        us4 o = { f2bf(v.x), f2bf(v.y), f2bf(v.z), f2bf(v.w) };
        *(us4*)&encB[(size_t)b * 2048 + k4 * 4] = o;
    } else {
        int j = idx - 65536;              // < 802816
        int row = j >> 7, k4 = j & 127;   // row = t*128 + b
        int t = row >> 7, b = row & 127;
        int tok = capsS[b * 50 + t];
        f32x4 v = *(const f32x4*)&embW[(size_t)tok * 512 + k4 * 4];
        us4 o = { f2bf(v.x), f2bf(v.y), f2bf(v.z), f2bf(v.w) };
        *(us4*)&Xemb[(size_t)row * 512 + k4 * 4] = o;
    }
}

// ---- shared 128x128 tile GEMM body (plain loads, full 128 valid rows both sides) ----
__device__ __forceinline__ void tile_gemm_plain(
    const u16* __restrict__ A, int lda, const u16* __restrict__ B, int ldb,
    int K, int tid, u16 (*As)[40], u16 (*Bs)[40], f32x4 acc[4][4])
{
    const int w = tid >> 6, l = tid & 63;
    const int wr = (w >> 1) * 64, wc = (w & 1) * 64;
    const int lr = l & 15, lg = l >> 4;
    for (int k0 = 0; k0 < K; k0 += 32) {
        __syncthreads();
        #pragma unroll
        for (int i = 0; i < 2; i++) {
            int L = tid * 8 + i * 2048;
            int r = L >> 5, c = L & 31;
            *(short8*)&As[r][c] = *(const short8*)&A[(size_t)r * lda + k0 + c];
            *(short8*)&Bs[r][c] = *(const short8*)&B[(size_t)r * ldb + k0 + c];
        }
        __syncthreads();
        short8 af[4], bfr[4];
        #pragma unroll
        for (int m = 0; m < 4; m++) af[m] = *(const short8*)&As[wr + m * 16 + lr][lg * 8];
        #pragma unroll
        for (int n = 0; n < 4; n++) bfr[n] = *(const short8*)&Bs[wc + n * 16 + lr][lg * 8];
        #pragma unroll
        for (int m = 0; m < 4; m++)
            #pragma unroll
            for (int n = 0; n < 4; n++)
                acc[m][n] = __builtin_amdgcn_mfma_f32_16x16x32_bf16(af[m], bfr[n], acc[m][n], 0, 0, 0);
    }
}

// ---------------- fused persistent kernel (round-14 proven structure) ----------------
// blocks 0..63:   LSTM producers. Per-WG FLAG (no RMW): init posts 1, step t posts
//                 t+2 (after draining only h stores; HnewC stores deferred past the
//                 post, covered by the next step's drain), final post TM+2.
//                 Gate: 16 parallel flag lanes + lane 16 polling xcnt[t].
// blocks 64..255: consumers. Phase 1: 784 X tiles (post xcnt[t]). Phase 2: fc
//                 column-owner; gate = 64-lane flag read >= tmax+3, CACHED
//                 (monotonic flags -> skip polls once satisfied); gate-waits
//                 consumed by zero-fill (non-temporal stores).
__global__ __launch_bounds__(256, 1) void lstm_fc(
    const u16* __restrict__ Whh, float* __restrict__ X,
    u16* __restrict__ hb0, u16* __restrict__ hb1,
    u16* __restrict__ HnewC,
    const int* __restrict__ decl, unsigned* __restrict__ flags,
    unsigned* __restrict__ xcnt,
    const int* __restrict__ offs, const int* __restrict__ rowmap,
    const int* __restrict__ maskmap,
    const u16* __restrict__ fcWB, const float* __restrict__ fcb,
    const u16* __restrict__ encB, const u16* __restrict__ WhcB,
    const u16* __restrict__ WihB, const u16* __restrict__ Xemb,
    const float* __restrict__ bsum,
    const float* __restrict__ ihb, const float* __restrict__ icb,
    float* __restrict__ out)
{
    extern __shared__ char smem[];
    const int tid = threadIdx.x;
    const int wg = blockIdx.x;

    if (wg < NLSTM) {
        // ======================= recurrence producer =======================
        u16 (*As)[520] = (u16(*)[520])smem;              // 33280 B
        u16 (*Bsi)[520] = (u16(*)[520])(smem + 33280);   // 33280 B (init only)
        const int rb = wg >> 4, cb = wg & 15;
        const int w = tid >> 6, l = tid & 63;
        const int hi = w >> 1, lo = w & 1;
        const int lr = l & 15, lg = l >> 4;
        unsigned* myflag = &flags[(rb * 16 + cb) * 32];

        const int col = cb * 32 + lo * 16 + lr;
        int rowg[4];
        #pragma unroll
        for (int i = 0; i < 4; i++) rowg[i] = rb * 32 + hi * 16 + lg * 4 + i;

        // ---- init: h0/c0 for this WG's 32x32 patches (K=2048, 4 chunks) ----
        f32x4 acch = {}, accc = {};
        for (int kq = 0; kq < 4; kq++) {
            __syncthreads();
            #pragma unroll
            for (int i = 0; i < 8; i++) {
                int L = tid * 8 + i * 2048;
                int rr = L >> 9, cc = L & 511;
                *(short8*)&As[rr][cc] =
                    *(const short8*)&encB[(size_t)(rb * 32 + rr) * 2048 + kq * 512 + cc];
                *(short8*)&Bsi[rr][cc] =
                    *(const short8*)&WhcB[(size_t)(cb * 32 + rr) * 2048 + kq * 512 + cc];
            }
            __syncthreads();
            #pragma unroll
            for (int kk = 0; kk < 16; kk++) {
                short8 a = *(const short8*)&As[hi * 16 + lr][kk * 32 + lg * 8];
                short8 b = *(const short8*)&Bsi[lo * 16 + lr][kk * 32 + lg * 8];
                acch = __builtin_amdgcn_mfma_f32_16x16x32_bf16(a, b, acch, 0, 0, 0);
            }
            __syncthreads();
            #pragma unroll
            for (int i = 0; i < 8; i++) {
                int L = tid * 8 + i * 2048;
                int rr = L >> 9, cc = L & 511;
                *(short8*)&Bsi[rr][cc] =
                    *(const short8*)&WhcB[(size_t)(512 + cb * 32 + rr) * 2048 + kq * 512 + cc];
            }
            __syncthreads();
            #pragma unroll
            for (int kk = 0; kk < 16; kk++) {
                short8 a = *(const short8*)&As[hi * 16 + lr][kk * 32 + lg * 8];
                short8 b = *(const short8*)&Bsi[lo * 16 + lr][kk * 32 + lg * 8];
                accc = __builtin_amdgcn_mfma_f32_16x16x32_bf16(a, b, accc, 0, 0, 0);
            }
        }

        int edec[4];
        f32x4 creg;
        us4 hreg;
        #pragma unroll
        for (int i = 0; i < 4; i++) {
            edec[i] = decl[rowg[i]];
            creg[i] = accc[i] + icb[col];
            hreg[i] = f2bf(acch[i] + ihb[col]);
            st_cp16(&hb0[(size_t)rowg[i] * 512 + col], (unsigned)hreg[i]);
        }
        asm volatile("s_waitcnt vmcnt(0)" ::: "memory");
        __syncthreads();
        if (tid == 0) st_cp32u(myflag, 1u);   // init published

        // ---- Whh fragments into registers (plain; L2/L3) ----
        short8 bq[4][16];
        #pragma unroll
        for (int q = 0; q < 4; q++) {
            const u16* base = &Whh[(size_t)(q * 512 + cb * 32 + lo * 16 + lr) * 512 + lg * 8];
            #pragma unroll
            for (int kk = 0; kk < 16; kk++)
                bq[q][kk] = *(const short8*)&base[kk * 32];
        }
        #pragma unroll
        for (int q = 0; q < 4; q++)
            #pragma unroll
            for (int kk = 0; kk < 16; kk++)
                asm volatile("" : "+v"(bq[q][kk]));   // pin: no remat of weight loads

        for (int t = 0; t < TM; t++) {
            const u16* hin = (t & 1) ? hb1 : hb0;
            u16* hout = (t & 1) ? hb0 : hb1;

            // gate: 16 flag lanes (h(t-1) within group) + lane 16 (X[t])
            if (tid < 64) {
                unsigned tgt_h = (unsigned)(t + 1);
                while (true) {
                    bool ok = true;
                    if (tid < 16)
                        ok = (ld_cp32_wait(&flags[(rb * 16 + tid) * 32]) >= tgt_h);
                    else if (tid == 16)
                        ok = (ld_cp32_wait(&xcnt[t * 32]) >= 16u);
                    if (__all(ok)) break;
                }
            }
            __syncthreads();

            // X[t] gate addends: plain loads (first touch fresh), overlap staging
            float xq[4][4];
            #pragma unroll
            for (int q = 0; q < 4; q++)
                #pragma unroll
                for (int i = 0; i < 4; i++)
                    xq[q][i] = X[(size_t)t * 262144 + (size_t)rowg[i] * 2048 + q * 512 + col];
            int offt = offs[t];

            // stage 32x512 h tile: 8 pipelined sc0sc1 x4 loads, one drain, LDS writes
            short8 tmp[8];
            #pragma unroll
            for (int i = 0; i < 8; i++) {
                int L = i * 256 + tid;          // 16B-chunk index; 2048 total
                int rr = L >> 6, cc = (L & 63) * 8;
                tmp[i] = ld_cp128(&hin[(size_t)(rb * 32 + rr) * 512 + cc]);
            }
            asm volatile("s_waitcnt vmcnt(0)" ::: "memory");
            __builtin_amdgcn_sched_barrier(0);
            #pragma unroll
            for (int i = 0; i < 8; i++) {
                int L = i * 256 + tid;
                int rr = L >> 6, cc = (L & 63) * 8;
                *(short8*)&As[rr][cc] = tmp[i];
            }
            __syncthreads();

            f32x4 acc[4] = {};
            #pragma unroll
            for (int kk = 0; kk < 16; kk++) {
                short8 a = *(const short8*)&As[hi * 16 + lr][kk * 32 + lg * 8];
                acc[0] = __builtin_amdgcn_mfma_f32_16x16x32_bf16(a, bq[0][kk], acc[0], 0, 0, 0);
                acc[1] = __builtin_amdgcn_mfma_f32_16x16x32_bf16(a, bq[1][kk], acc[1], 0, 0, 0);
                acc[2] = __builtin_amdgcn_mfma_f32_16x16x32_bf16(a, bq[2][kk], acc[2], 0, 0, 0);
                acc[3] = __builtin_amdgcn_mfma_f32_16x16x32_bf16(a, bq[3][kk], acc[3], 0, 0, 0);
            }

            // lane-local epilogue; h stores sc0sc1 BEFORE the drain
            #pragma unroll
            for (int i = 0; i < 4; i++) {
                int act = (t < edec[i]);
                float iv = fsigm(acc[0][i] + xq[0][i]);
                float fv = fsigm(acc[1][i] + xq[1][i]);
                float gv = ftanh(acc[2][i] + xq[2][i]);
                float ov = fsigm(acc[3][i] + xq[3][i]);
                float cn = fv * creg[i] + iv * gv;
                float hn_f = ov * ftanh(cn);
                if (act) {
                    creg[i] = cn;
                    hreg[i] = f2bf(hn_f);
                }
                st_cp16(&hout[(size_t)rowg[i] * 512 + col], (unsigned)hreg[i]);
            }

            // drain h stores only, post flag, THEN issue HnewC stores (deferred;
            // covered by next step's drain / final drain)
            asm volatile("s_waitcnt vmcnt(0)" ::: "memory");
            __syncthreads();
            if (tid == 0) st_cp32u(myflag, (unsigned)(t + 2));
            #pragma unroll
            for (int i = 0; i < 4; i++)
                if (t < edec[i])
                    st_cp16(&HnewC[(size_t)(offt + rowg[i]) * 512 + col], (unsigned)hreg[i]);
        }

        // final: drain deferred HnewC stores, publish terminal flag
        asm volatile("s_waitcnt vmcnt(0)" ::: "memory");
        __syncthreads();
        if (tid == 0) st_cp32u(myflag, (unsigned)(TM + 2));
    } else {
        // ======================= consumer =======================
        const int f = wg - NLSTM;
        const int w = tid >> 6, l = tid & 63;
        const int wr = (w >> 1) * 64, wc = (w & 1) * 64;
        const int lr = l & 15, lg = l >> 4;

        int nrC = offs[49];
        int nzero = 6272 - nrC;
        int nrt = (nrC + 127) >> 7;

        // ---- phase 1: X tiles (784 jobs round-robin) ----
        {
            u16 (*As)[40] = (u16(*)[40])smem;
            u16 (*Bs)[40] = (u16(*)[40])(smem + 10240);
            for (int j = f; j < 784; j += NFC) {
                int tt = j >> 4, cbx = j & 15;
                f32x4 acc[4][4] = {};
                tile_gemm_plain(Xemb + (size_t)tt * 128 * 512, 512,
                                WihB + (size_t)cbx * 128 * 512, 512,
                                512, tid, As, Bs, acc);
                #pragma unroll
                for (int m = 0; m < 4; m++)
                    #pragma unroll
                    for (int n = 0; n < 4; n++)
                        #pragma unroll
                        for (int i = 0; i < 4; i++) {
                            int row = wr + m * 16 + lg * 4 + i;
                            int colg = cbx * 128 + wc + n * 16 + lr;
                            st_cp32f(&X[(size_t)tt * 262144 + (size_t)row * 2048 + colg],
                                     acc[m][n][i] + bsum[colg]);
                        }
                asm volatile("s_waitcnt vmcnt(0)" ::: "memory");
                __syncthreads();
                if (tid == 0) atomicAdd(&xcnt[tt * 32], 1u);
            }
        }

        // ---- phase 2: fc column-owner; B panel resident in LDS; gate-waits
        //      consumed by opportunistic zero-fill; gate CACHED (flags monotonic) ----
        int c = f % 79;               // owned column tile
        int sub = f / 79;             // 0,1 (2 only for c < 34)
        int gsize = (c < 34) ? 3 : 2;

        u16 (*BT)[520] = (u16(*)[520])smem;                 // 133120 B
        unsigned* s_rdy = (unsigned*)(smem + 133120);       // 1 u32
        __syncthreads();   // phase-1 LDS fully retired before overwrite
        #pragma unroll
        for (int i = 0; i < 32; i++) {
            int L = i * 256 + tid;            // short8 index; 8192 = 128 x 64
            int rr = L >> 6, cc = (L & 63) * 8;
            int gn = c * 128 + rr;
            short8 b = {};
            if (gn < NV) b = *(const short8*)&fcWB[(size_t)gn * 512 + cc];
            *(short8*)&BT[rr][cc] = b;
        }
        __syncthreads();

        int znext = f;   // this consumer's masked-row zero jobs: f, f+NFC, ...
        f32x4 zv = {};
        unsigned satisfied = 0;   // cached max satisfied gate target (flags monotonic)

        for (int rt = sub; rt < nrt; rt += gsize) {
            int lastrow = min(rt * 128 + 127, nrC - 1);
            int tmax = rowmap[lastrow] >> 7;
            unsigned tgt = (unsigned)(tmax + 3);   // deferred-HnewC visibility

            // gate with productive waiting (skipped entirely once satisfied >= tgt)
            while (satisfied < tgt) {
                bool ok = (tid < 64) ? (ld_cp32_wait(&flags[tid * 32]) >= tgt) : true;
                int allv = __all(ok);
                if (tid == 0) *s_rdy = (unsigned)allv;
                __syncthreads();
                bool rdy = (*s_rdy != 0);
                __syncthreads();
                if (rdy) { satisfied = tgt; break; }
                if (znext < nzero) {
                    float* dst = out + (size_t)maskmap[znext] * 10000;
                    for (int i = tid; i < 2500; i += 256)
                        __builtin_nontemporal_store(zv, (f32x4*)&dst[i * 4]);
                    znext += NFC;
                } else {
                    __builtin_amdgcn_s_sleep(32);
                }
            }

            // barrier-free K-loop: A fragments direct global->reg, B from LDS
            f32x4 acc[4][4] = {};
            #pragma unroll
            for (int ks = 0; ks < 16; ks++) {
                short8 af[4], bfr[4];
                #pragma unroll
                for (int m = 0; m < 4; m++) {
                    int gr = rt * 128 + wr + m * 16 + lr;
                    short8 a = {};
                    if (gr < nrC)
                        a = *(const short8*)&HnewC[(size_t)gr * 512 + ks * 32 + lg * 8];
                    af[m] = a;
                }
                #pragma unroll
                for (int n = 0; n < 4; n++)
                    bfr[n] = *(const short8*)&BT[wc + n * 16 + lr][ks * 32 + lg * 8];
                #pragma unroll
                for (int m = 0; m < 4; m++)
                    #pragma unroll
                    for (int n = 0; n < 4; n++)
                        acc[m][n] = __builtin_amdgcn_mfma_f32_16x16x32_bf16(af[m], bfr[n], acc[m][n], 0, 0, 0);
            }

            #pragma unroll
            for (int m = 0; m < 4; m++)
                #pragma unroll
                for (int n = 0; n < 4; n++)
                    #pragma unroll
                    for (int i = 0; i < 4; i++) {
                        int row = rt * 128 + wr + m * 16 + lg * 4 + i;
                        int colg = c * 128 + wc + n * 16 + lr;
                        if (row < nrC && colg < NV) {
                            int map = rowmap[row];
                            int b = map & 127, tt = map >> 7;
                            __builtin_nontemporal_store(
                                acc[m][n][i] + fcb[colg],
                                &out[(size_t)(b * 49 + tt) * 10000 + colg]);
                        }
                    }
        }

        // leftover zero jobs
        while (znext < nzero) {
            float* dst = out + (size_t)maskmap[znext] * 10000;
            for (int i = tid; i < 2500; i += 256)
                __builtin_nontemporal_store(zv, (f32x4*)&dst[i * 4]);
            znext += NFC;
        }
    }
}

extern "C" void kernel_launch(void* const* d_in, const int* in_sizes, int n_in,
                              void* d_out, int out_size, void* d_ws, size_t ws_size,
                              hipStream_t stream) {
    const float* enc      = (const float*)d_in[0];
    const int*   captions = (const int*)d_in[1];
    const int*   caplens  = (const int*)d_in[2];
    const float* embW     = (const float*)d_in[3];
    const float* Wih      = (const float*)d_in[4];
    const float* Whh      = (const float*)d_in[5];
    const float* bih      = (const float*)d_in[6];
    const float* bhh      = (const float*)d_in[7];
    const float* fcW      = (const float*)d_in[8];
    const float* fcb      = (const float*)d_in[9];
    const float* ihW      = (const float*)d_in[10];
    const float* ihb      = (const float*)d_in[11];
    const float* icW      = (const float*)d_in[12];
    const float* icb      = (const float*)d_in[13];
    float* out = (float*)d_out;

    char* ws = (char*)d_ws;
    u16*   WihB = (u16*)(ws + 0);
    u16*   WhhB = (u16*)(ws + 2097152);
    u16*   fcWB = (u16*)(ws + 4194304);
    u16*   WhcB = (u16*)(ws + 14434304);
    u16*   encB = (u16*)(ws + 18628608);
    u16*   Xemb = (u16*)(ws + 19152896);
    float* X    = (float*)(ws + 25575424);
    u16*   HnewC= (u16*)(ws + 76955648);
    u16*   hb0  = (u16*)(ws + 83378176);
    u16*   hb1  = (u16*)(ws + 83509248);
    unsigned* flags = (unsigned*)(ws + 83640320);   // 64 flag lines x 128B (old cf region)
    int*   sidx = (int*)(ws + 83902464);
    int*   decl = (int*)(ws + 83902976);
    int*   capsS= (int*)(ws + 83903488);
    float* bsum = (float*)(ws + 83929088);
    int*   offs   = (int*)(ws + 83938304);          // 50 ints; offs[49] = nrowsC
    int*   rowmap = (int*)(ws + 83938560);          // 6272 ints
    int*   maskmap= (int*)(ws + 83963648);          // 6272 ints
    unsigned* xcnt = (unsigned*)(ws + 83988736);    // 49 counters @ t*32

    k_sort<<<1, 128, 0, stream>>>(caplens, captions, bih, bhh, sidx, decl, capsS, bsum,
                                  out + 62720000, flags, xcnt, offs, rowmap, maskmap);
    k_cvt<<<9096, 256, 0, stream>>>(Wih, Whh, fcW, ihW, icW, WihB, WhhB, fcWB, WhcB);
    k_gather<<<3392, 256, 0, stream>>>(enc, embW, sidx, capsS, encB, Xemb);
    // fused: h0/c0 (in producers) + X precompute + zero-fill + 49 steps + fc GEMM
    lstm_fc<<<NLSTM + NFC, 256, SMEM_BYTES, stream>>>(
        WhhB, X, hb0, hb1, HnewC, decl, flags, xcnt, offs, rowmap, maskmap,
        fcWB, fcb, encB, WhcB, WihB, Xemb, bsum, ihb, icb, out);
}